// Round 17
// baseline (182.342 us; speedup 1.0000x reference)
//
#include <hip/hip_runtime.h>
#include <math.h>

// KNN (weights='distance'): B=1024 queries, N=100000 train, D=64, K=16, 10 classes.
// s-domain: s = dot - t2/2 entirely in MFMA (C-init = -t2/2); bigger = closer.
// memset(done) -> prep (cvt | sample role-split; last sample block per qb
// computes theta in-block) -> filter (64 q/block, 1024-block balanced grid,
// glds 3-slot ring depth-2, counted vmcnt, XCD-swizzle) -> vote.

constexpr int D        = 64;
constexpr int K        = 16;
constexpr int NCLS     = 10;
constexpr int CHUNKLEN = 1664;   // points per filter chunk; wave owns 416 (26 sgs of 16)
constexpr int NCHUNK   = 64;     // 64*1664 = 106496 >= 100000; %8==0; grid 16x64 = 1024 = 4/CU
constexpr int NPAD     = NCHUNK * CHUNKLEN + 64;  // 106560 (staging overrun room)
constexpr int NSUB     = 64;     // sample subchunks
constexpr int SUBLEN   = 128;    // sample points per subchunk (8192 total)
constexpr int SLOT     = 23;     // pair slots per (query, chunk); lambda ~3.25
constexpr int MSEL     = 48;     // approx candidates kept for exact rescore
constexpr int SGPTS    = 16;     // points per stage-group
constexpr int SGBYTES  = SGPTS * 128;             // 2048
constexpr int SLOTB    = SGBYTES + 256;           // ring slot: A-tile + nh = 2304
constexpr int NSG      = CHUNKLEN / 4 / SGPTS;    // 26 stage-groups per wave
constexpr int NCVT     = (NPAD * 4) / 256;        // 1665 cvt blocks (exact)

typedef __attribute__((ext_vector_type(8))) short bf16x8_t;
typedef __attribute__((ext_vector_type(4))) float f32x4_t;
typedef unsigned short ushort_t;

__device__ __forceinline__ ushort_t f32_to_bf16_rne(float f) {
  unsigned int u = __float_as_uint(f);
  unsigned int r = u + 0x7FFFu + ((u >> 16) & 1u);
  return (ushort_t)(r >> 16);
}

__device__ __forceinline__ bf16x8_t pack_bf16x8(float4 a, float4 b) {
  union { ushort_t u[8]; bf16x8_t v; } r;
  r.u[0] = f32_to_bf16_rne(a.x); r.u[1] = f32_to_bf16_rne(a.y);
  r.u[2] = f32_to_bf16_rne(a.z); r.u[3] = f32_to_bf16_rne(a.w);
  r.u[4] = f32_to_bf16_rne(b.x); r.u[5] = f32_to_bf16_rne(b.y);
  r.u[6] = f32_to_bf16_rne(b.z); r.u[7] = f32_to_bf16_rne(b.w);
  return r.v;
}

__device__ __forceinline__ void glds16(const void* g, void* l) {
  __builtin_amdgcn_global_load_lds(
      (const __attribute__((address_space(1))) void*)g,
      (__attribute__((address_space(3))) void*)l, 16, 0, 0);
}
__device__ __forceinline__ void glds4(const void* g, void* l) {
  __builtin_amdgcn_global_load_lds(
      (const __attribute__((address_space(1))) void*)g,
      (__attribute__((address_space(3))) void*)l, 4, 0, 0);
}

// ---- prep: role-split. Blocks [0,NCVT): train fp32->bf16 + t2 + nt2h
//      (pad rows: tb=0, t2=INF, nt2h=-INF). Blocks [NCVT,+1024): sample role;
//      the LAST sample block of each qb (device-scope release/acquire) merges
//      all 64 sub-lists and writes theta for its 64 queries. ----
__global__ __launch_bounds__(256) void knn_prep(
    const float* __restrict__ train, const float* __restrict__ x,
    ushort_t* __restrict__ tb, float* __restrict__ t2,
    float* __restrict__ nt2h, float* __restrict__ samp,
    int* __restrict__ done, float* __restrict__ theta, int N)
{
  __shared__ float nh_l[4][16];
  __shared__ int lastFlag;
  const int tid = threadIdx.x;

  if ((int)blockIdx.x < NCVT) {          // ---- cvt role ----
    int gid = blockIdx.x * 256 + tid;
    int row = gid >> 2, qt = gid & 3;
    ushort_t* dst = tb + (size_t)row * D + qt * 16;
    if (row >= N) {
      uint2 z = make_uint2(0u, 0u);
      #pragma unroll
      for (int i = 0; i < 4; ++i) *reinterpret_cast<uint2*>(dst + i * 4) = z;
      if (qt == 0) { t2[row] = INFINITY; nt2h[row] = -INFINITY; }
      return;
    }
    const float* src = train + (size_t)row * D + qt * 16;
    float nrm = 0.f;
    #pragma unroll
    for (int i = 0; i < 4; ++i) {
      float4 v = *reinterpret_cast<const float4*>(src + i * 4);
      nrm = fmaf(v.x, v.x, nrm); nrm = fmaf(v.y, v.y, nrm);
      nrm = fmaf(v.z, v.z, nrm); nrm = fmaf(v.w, v.w, nrm);
      uint2 hh = make_uint2(
        (unsigned)f32_to_bf16_rne(v.x) | ((unsigned)f32_to_bf16_rne(v.y) << 16),
        (unsigned)f32_to_bf16_rne(v.z) | ((unsigned)f32_to_bf16_rne(v.w) << 16));
      *reinterpret_cast<uint2*>(dst + i * 4) = hh;
    }
    nrm += __shfl_xor(nrm, 1);
    nrm += __shfl_xor(nrm, 2);
    if (qt == 0) { t2[row] = nrm; nt2h[row] = -0.5f * nrm; }
    return;
  }

  // ---- sample role (reads fp32 train directly; independent of cvt) ----
  const int bid2 = blockIdx.x - NCVT;
  const int w = tid >> 6, lane = tid & 63;
  const int lh = lane & 15, lg = lane >> 4;
  const int qb = bid2 & 15, sub = bid2 >> 4;
  const int q = qb * 64 + w * 16 + lh;

  const float* xrp = x + (size_t)q * D + lg * 8;
  bf16x8_t B0 = pack_bf16x8(*reinterpret_cast<const float4*>(xrp),
                            *reinterpret_cast<const float4*>(xrp + 4));
  bf16x8_t B1 = pack_bf16x8(*reinterpret_cast<const float4*>(xrp + 32),
                            *reinterpret_cast<const float4*>(xrp + 36));

  float Ld[4] = {-INFINITY, -INFINITY, -INFINITY, -INFINITY};  // descending
  const int pstart = sub * SUBLEN;

  for (int j = 0; j < SUBLEN / 16; ++j) {          // 8 groups of 16 points
    const float* tr = train + (size_t)(pstart + j * 16 + lh) * D;
    float4 f0 = *reinterpret_cast<const float4*>(tr + lg * 8);
    float4 f1 = *reinterpret_cast<const float4*>(tr + lg * 8 + 4);
    float4 f2 = *reinterpret_cast<const float4*>(tr + 32 + lg * 8);
    float4 f3 = *reinterpret_cast<const float4*>(tr + 32 + lg * 8 + 4);
    bf16x8_t A0 = pack_bf16x8(f0, f1);
    bf16x8_t A1 = pack_bf16x8(f2, f3);
    float pn = 0.f;
    pn = fmaf(f0.x, f0.x, pn); pn = fmaf(f0.y, f0.y, pn);
    pn = fmaf(f0.z, f0.z, pn); pn = fmaf(f0.w, f0.w, pn);
    pn = fmaf(f1.x, f1.x, pn); pn = fmaf(f1.y, f1.y, pn);
    pn = fmaf(f1.z, f1.z, pn); pn = fmaf(f1.w, f1.w, pn);
    pn = fmaf(f2.x, f2.x, pn); pn = fmaf(f2.y, f2.y, pn);
    pn = fmaf(f2.z, f2.z, pn); pn = fmaf(f2.w, f2.w, pn);
    pn = fmaf(f3.x, f3.x, pn); pn = fmaf(f3.y, f3.y, pn);
    pn = fmaf(f3.z, f3.z, pn); pn = fmaf(f3.w, f3.w, pn);
    pn += __shfl_xor(pn, 16);
    pn += __shfl_xor(pn, 32);      // full row norm at every lg lane
    if (lg == 0) nh_l[w][lh] = -0.5f * pn;   // within-wave LDS bounce
    float4 nh = *reinterpret_cast<const float4*>(&nh_l[w][lg * 4]);
    f32x4_t c = {nh.x, nh.y, nh.z, nh.w};
    c = __builtin_amdgcn_mfma_f32_16x16x32_bf16(A0, B0, c, 0, 0, 0);
    c = __builtin_amdgcn_mfma_f32_16x16x32_bf16(A1, B1, c, 0, 0, 0);
    #pragma unroll
    for (int r = 0; r < 4; ++r) {
      float sv = c[r];
      if (sv > Ld[3]) {
        Ld[3] = sv;
        if (Ld[3] > Ld[2]) { float s_ = Ld[3]; Ld[3] = Ld[2]; Ld[2] = s_; }
        if (Ld[2] > Ld[1]) { float s_ = Ld[2]; Ld[2] = Ld[1]; Ld[1] = s_; }
        if (Ld[1] > Ld[0]) { float s_ = Ld[1]; Ld[1] = Ld[0]; Ld[0] = s_; }
      }
    }
  }

  float* outp = samp + (size_t)q * (NSUB * 16) + sub * 16 + lg * 4;
  *reinterpret_cast<float4*>(outp) = make_float4(Ld[0], Ld[1], Ld[2], Ld[3]);

  // ---- last-block-per-qb theta merge (device-scope release/acquire) ----
  __syncthreads();
  if (tid == 0) {
    __threadfence();                          // release: samp writes -> device
    int old = atomicAdd(&done[qb], 1);        // device-scope RMW
    lastFlag = (old == 63);
  }
  __syncthreads();
  if (lastFlag) {
    __threadfence();                          // acquire: discard stale cache
    // wave w handles queries qb*64 + w*16 .. +16 (one query at a time;
    // lane = sub list, 4 descending-4 runs each; 16 rounds of wave-max pop)
    for (int i = 0; i < 16; ++i) {
      const int qq = qb * 64 + w * 16 + i;
      const float* s = samp + (size_t)qq * (NSUB * 16) + lane * 16;
      float4 p0 = *reinterpret_cast<const float4*>(s);
      float4 p1 = *reinterpret_cast<const float4*>(s + 4);
      float4 p2 = *reinterpret_cast<const float4*>(s + 8);
      float4 p3 = *reinterpret_cast<const float4*>(s + 12);
      float L0[4] = {p0.x, p0.y, p0.z, p0.w};
      float L1[4] = {p1.x, p1.y, p1.z, p1.w};
      float L2[4] = {p2.x, p2.y, p2.z, p2.w};
      float L3[4] = {p3.x, p3.y, p3.z, p3.w};
      float th = -INFINITY;
      for (int r = 0; r < K; ++r) {
        float bd = fmaxf(fmaxf(L0[0], L1[0]), fmaxf(L2[0], L3[0]));
        #pragma unroll
        for (int sdx = 0; sdx < 6; ++sdx) bd = fmaxf(bd, __shfl_xor(bd, 32 >> sdx));
        if (L0[0] == bd) { L0[0] = L0[1]; L0[1] = L0[2]; L0[2] = L0[3]; L0[3] = -INFINITY; }
        if (L1[0] == bd) { L1[0] = L1[1]; L1[1] = L1[2]; L1[2] = L1[3]; L1[3] = -INFINITY; }
        if (L2[0] == bd) { L2[0] = L2[1]; L2[1] = L2[2]; L2[2] = L2[3]; L2[3] = -INFINITY; }
        if (L3[0] == bd) { L3[0] = L3[1]; L3[1] = L3[2]; L3[2] = L3[3]; L3[3] = -INFINITY; }
        th = bd;
      }
      if (lane == 0) theta[qq] = th;
    }
  }
}

// ---- filter: grid (16,NCHUNK)=1024 blocks (exactly 4/CU, balanced),
//      XCD-swizzled (all 16 blocks of a chunk on one XCD). Block owns 64
//      queries; wave owns 416 pts = 26 sgs of 16, staged via glds 3-slot
//      ring, depth-2 prefetch, counted vmcnt(6). Accept s >= theta. ----
__global__ __launch_bounds__(256) void knn_filter(
    const ushort_t* __restrict__ tb, const float* __restrict__ x,
    const float* __restrict__ nt2h, const float* __restrict__ theta,
    int* __restrict__ cnts, int2* __restrict__ cand2)
{
  __shared__ char ring[4][3][SLOTB];     // 27648 B
  __shared__ int  cnt_l[64];
  __shared__ int2 list_p[64][SLOT];      // 11776 B -> total ~39.7 KB, 4 blk/CU

  const int tid = threadIdx.x;
  const int w = tid >> 6, lane = tid & 63;
  const int lh = lane & 15, lg = lane >> 4;

  // XCD-aware bijective remap (NCHUNK % 8 == 0)
  const int d   = blockIdx.x + 16 * blockIdx.y;    // 0..1023
  const int xcd = d & 7;
  const int t_  = d >> 3;                          // 0..127
  const int qb  = t_ & 15;
  const int ch  = ((t_ >> 4) << 3) | xcd;          // 0..63

  const int q0  = qb * 64;
  const int wp0 = ch * CHUNKLEN + w * (CHUNKLEN / 4);   // wave's 416-pt base

  if (tid < 64) cnt_l[tid] = 0;
  __syncthreads();

  bf16x8_t Bq0[4], Bq1[4];
  float th[4];
  #pragma unroll
  for (int ct = 0; ct < 4; ++ct) {
    const float* xrp = x + (size_t)(q0 + ct * 16 + lh) * D + lg * 8;
    Bq0[ct] = pack_bf16x8(*reinterpret_cast<const float4*>(xrp),
                          *reinterpret_cast<const float4*>(xrp + 4));
    Bq1[ct] = pack_bf16x8(*reinterpret_cast<const float4*>(xrp + 32),
                          *reinterpret_cast<const float4*>(xrp + 36));
    th[ct] = theta[q0 + ct * 16 + lh];
  }

  char* myring = &ring[w][0][0];
  const char*  gA = (const char*)(tb + (size_t)wp0 * D);
  const float* gN = nt2h + wp0;
  // staging: inst k covers lds [k*1024,+1024) = 8 rows; lane l holds
  // row k*8 + l/8, swizzled 16B-slot (l&7)^(l>>3). Pre-swizzled global src.
  // => LDS[row][j] = global[row][j ^ (row&7)]; read applies the same XOR.
  const int rowoff = (lane >> 3) * 128;
  const int swz    = (((lane & 7) ^ (lane >> 3)) << 4);
  const int lhx    = lh & 7;

  #define ISSUE(SG)                                                              \
    {                                                                            \
      char* sb = myring + ((SG) % 3) * SLOTB;                                    \
      const char* ga = gA + (size_t)(SG) * SGBYTES;                              \
      glds16(ga + rowoff + swz,        sb);                                      \
      glds16(ga + 1024 + rowoff + swz, sb + 1024);                               \
      glds4 (gN + (SG) * SGPTS + lane, sb + 2048);                               \
    }

  #define COMPUTE(SG)                                                            \
    {                                                                            \
      const char* sb = myring + ((SG) % 3) * SLOTB;                              \
      bf16x8_t A0 = *reinterpret_cast<const bf16x8_t*>(                          \
          sb + lh * 128 + ((lg ^ lhx) << 4));                                    \
      bf16x8_t A1 = *reinterpret_cast<const bf16x8_t*>(                          \
          sb + lh * 128 + (((lg + 4) ^ lhx) << 4));                              \
      float4 nh = *reinterpret_cast<const float4*>(sb + 2048 + lg * 16);         \
      const int pg = wp0 + (SG) * SGPTS + lg * 4;                                \
      _Pragma("unroll")                                                          \
      for (int ct = 0; ct < 4; ++ct) {                                           \
        f32x4_t c = {nh.x, nh.y, nh.z, nh.w};                                    \
        c = __builtin_amdgcn_mfma_f32_16x16x32_bf16(A0, Bq0[ct], c, 0, 0, 0);    \
        c = __builtin_amdgcn_mfma_f32_16x16x32_bf16(A1, Bq1[ct], c, 0, 0, 0);    \
        float mx = fmaxf(fmaxf(c[0], c[1]), fmaxf(c[2], c[3]));                  \
        if (mx >= th[ct]) {                                                      \
          const int qloc = ct * 16 + lh;                                         \
          _Pragma("unroll")                                                      \
          for (int r = 0; r < 4; ++r) {                                          \
            if (c[r] >= th[ct]) {                                                \
              int pos = atomicAdd(&cnt_l[qloc], 1);                              \
              if (pos < SLOT)                                                    \
                list_p[qloc][pos] = make_int2(pg + r, __float_as_int(c[r]));     \
            }                                                                    \
          }                                                                      \
        }                                                                        \
      }                                                                          \
    }

  asm volatile("s_waitcnt vmcnt(0)" ::: "memory");   // drain prologue loads
  ISSUE(0);
  ISSUE(1);
  #pragma unroll
  for (int it = 0; it < NSG; ++it) {
    if (it < NSG - 2) {
      ISSUE(it + 2);
      asm volatile("s_waitcnt vmcnt(6)" ::: "memory");  // sg 'it' landed; 2 ahead in flight
    } else if (it == NSG - 2) {
      asm volatile("s_waitcnt vmcnt(3)" ::: "memory");
    } else {
      asm volatile("s_waitcnt vmcnt(0)" ::: "memory");
    }
    COMPUTE(it);
  }
  #undef ISSUE
  #undef COMPUTE

  __syncthreads();
  if (tid < 64) {
    int n = cnt_l[tid]; if (n > SLOT) n = SLOT;
    size_t o = (size_t)(q0 + tid) * NCHUNK + ch;
    cnts[o] = n;
    for (int j = 0; j < n; ++j) cand2[o * SLOT + j] = list_p[tid][j];
  }
}

// ---- vote: one block per query. Compact (idx,s) pairs, rank-by-count
//      (unroll-4, sentinel pad) -> top-MSEL, exact rescore (4 thr/cand),
//      exact (d2,idx)-lex top-16, weighted vote. ----
__global__ __launch_bounds__(256) void knn_vote(
    const float* __restrict__ x, const float* __restrict__ train,
    const float* __restrict__ t2, const int* __restrict__ labels,
    const int* __restrict__ cnts, const int2* __restrict__ cand2,
    float* __restrict__ out, int B, int N)
{
  __shared__ int2  cpair[NCHUNK * SLOT + 4];   // 1476 pairs
  __shared__ float sortd[MSEL];
  __shared__ int   sorti[MSEL];
  __shared__ float xs[D];
  __shared__ int   total_s;
  __shared__ float x2_s;

  const int tid = threadIdx.x;
  const int w = tid >> 6, lane = tid & 63;
  const int q = blockIdx.x;

  if (tid == 0) total_s = 0;
  if (tid < D) xs[tid] = x[(size_t)q * D + tid];
  if (tid < MSEL) { sortd[tid] = INFINITY; sorti[tid] = 0x7fffffff; }
  __syncthreads();

  if (w == 0) {
    float v = xs[lane];
    float s = v * v;
    #pragma unroll
    for (int o = 32; o > 0; o >>= 1) s += __shfl_xor(s, o);
    if (lane == 0) x2_s = s;
  }
  if (tid < NCHUNK) {
    int n = cnts[(size_t)q * NCHUNK + tid];
    int base = atomicAdd(&total_s, n);
    const int2* src = cand2 + ((size_t)q * NCHUNK + tid) * SLOT;
    for (int j = 0; j < n; ++j) cpair[base + j] = src[j];
  }
  __syncthreads();

  const int total = total_s;
  const int totalPad = (total + 3) & ~3;
  const float x2 = x2_s;
  if (tid < totalPad - total)
    cpair[total + tid] = make_int2(0x7fffffff, __float_as_int(-INFINITY));
  __syncthreads();

  for (int j = tid; j < total; j += 256) {
    int2 mine = cpair[j];
    float ms = __int_as_float(mine.y);
    int   mi = mine.x;
    int rank = 0;
    for (int k = 0; k < totalPad; k += 4) {
      int2 o0 = cpair[k];     int2 o1 = cpair[k + 1];
      int2 o2 = cpair[k + 2]; int2 o3 = cpair[k + 3];
      float s0 = __int_as_float(o0.y), s1 = __int_as_float(o1.y);
      float s2 = __int_as_float(o2.y), s3 = __int_as_float(o3.y);
      rank += ((s0 > ms || (s0 == ms && o0.x < mi)) ? 1 : 0)
            + ((s1 > ms || (s1 == ms && o1.x < mi)) ? 1 : 0)
            + ((s2 > ms || (s2 == ms && o2.x < mi)) ? 1 : 0)
            + ((s3 > ms || (s3 == ms && o3.x < mi)) ? 1 : 0);
    }
    if (rank < MSEL) { sortd[rank] = ms; sorti[rank] = mi; }
  }
  __syncthreads();

  if (tid < MSEL * 4) {
    const int ci = tid >> 2, qt = tid & 3;
    const int idx = sorti[ci];
    float dot = 0.f;
    if (idx != 0x7fffffff) {
      const float* tr = train + (size_t)idx * D + qt * 16;
      #pragma unroll
      for (int i = 0; i < 4; ++i) {
        float4 tv = *reinterpret_cast<const float4*>(tr + i * 4);
        dot = fmaf(xs[qt * 16 + i * 4 + 0], tv.x, dot);
        dot = fmaf(xs[qt * 16 + i * 4 + 1], tv.y, dot);
        dot = fmaf(xs[qt * 16 + i * 4 + 2], tv.z, dot);
        dot = fmaf(xs[qt * 16 + i * 4 + 3], tv.w, dot);
      }
    }
    dot += __shfl_xor(dot, 1);
    dot += __shfl_xor(dot, 2);
    if (qt == 0)
      sortd[ci] = (idx != 0x7fffffff)
                ? fmaxf(x2 - 2.f * dot + t2[idx], 0.f) : INFINITY;
  }
  __syncthreads();

  if (w == 0) {
    float vd = (lane < MSEL) ? sortd[lane] : INFINITY;
    int   vi = (lane < MSEL) ? sorti[lane] : 0x7fffffff;
    float myD = INFINITY; int myI = 0;
    for (int r = 0; r < K; ++r) {
      float bd = vd; int bi = vi;
      #pragma unroll
      for (int s = 0; s < 6; ++s) {
        int off = 32 >> s;
        float od = __shfl_xor(bd, off);
        int   oi = __shfl_xor(bi, off);
        if (od < bd || (od == bd && oi < bi)) { bd = od; bi = oi; }
      }
      if (vd == bd && vi == bi) { vd = INFINITY; vi = 0x7fffffff; }
      if (lane == r) { myD = bd; myI = bi; }
    }

    int valid = (lane < K) && (myD < INFINITY) && (myI < N);
    float dist = sqrtf(fmaxf(myD, 0.f));
    int lab = labels[(valid && myI < N) ? myI : 0];
    int isz = (valid && dist == 0.f) ? 1 : 0;
    float wgt = 1.f / dist;

    float accw[NCLS]; float acci[NCLS]; int anyInf = 0;
    #pragma unroll
    for (int c = 0; c < NCLS; ++c) { accw[c] = 0.f; acci[c] = 0.f; }
    for (int r = 0; r < K; ++r) {
      int   vr   = __shfl(valid, r);
      int   labr = __shfl(lab, r);
      float wgtr = __shfl(wgt, r);
      int   iszr = __shfl(isz, r);
      if (vr) {
        anyInf |= iszr;
        #pragma unroll
        for (int c = 0; c < NCLS; ++c) {
          accw[c] += (labr == c) ? wgtr : 0.f;
          acci[c] += (labr == c && iszr) ? 1.f : 0.f;
        }
      }
    }

    if (lane == 0) {
      float proba[NCLS]; float s = 0.f;
      #pragma unroll
      for (int c = 0; c < NCLS; ++c) { proba[c] = anyInf ? acci[c] : accw[c]; s += proba[c]; }
      if (s == 0.f) s = 1.f;
      #pragma unroll
      for (int c = 0; c < NCLS; ++c) proba[c] = proba[c] / s;
      int best = 0; float bv = proba[0];
      #pragma unroll
      for (int c = 1; c < NCLS; ++c) if (proba[c] > bv) { bv = proba[c]; best = c; }
      out[q] = (float)best;
      #pragma unroll
      for (int c = 0; c < NCLS; ++c) out[B + q * NCLS + c] = proba[c];
    }
  }
}

extern "C" void kernel_launch(void* const* d_in, const int* in_sizes, int n_in,
                              void* d_out, int out_size, void* d_ws, size_t ws_size,
                              hipStream_t stream)
{
  const float* x      = (const float*)d_in[0];
  const float* train  = (const float*)d_in[1];
  const int*   labels = (const int*)d_in[2];
  float* out = (float*)d_out;

  const int B = in_sizes[0] / D;   // 1024
  const int N = in_sizes[2];       // 100000

  // workspace carve (16B-aligned), ~27 MB; samp ALIASES cand2 (theta consumed
  // inside prep before filter writes cand2 -- stream-ordered).
  char* ws = (char*)d_ws;
  size_t off = 0;
  ushort_t* train_bf = (ushort_t*)(ws + off); off += (size_t)NPAD * D * 2;           // 13.6 MB
  float*    t2       = (float*)(ws + off);    off += (size_t)NPAD * 4;               // 426 KB
  float*    nt2h     = (float*)(ws + off);    off += (size_t)NPAD * 4;               // 426 KB
  float*    theta    = (float*)(ws + off);    off += (size_t)B * 4;
  int*      done     = (int*)(ws + off);      off += 64;
  int*      cnts     = (int*)(ws + off);      off += (size_t)B * NCHUNK * 4;         // 256 KB
  int2*     cand2    = (int2*)(ws + off);     off += (size_t)B * NCHUNK * SLOT * 8;  // 12.1 MB
  float*    samp     = (float*)cand2;         // B*NSUB*16*4 = 4 MB <= cand2 region

  hipMemsetAsync(done, 0, 16 * sizeof(int), stream);
  knn_prep<<<NCVT + (B / 64) * NSUB, 256, 0, stream>>>(
      train, x, train_bf, t2, nt2h, samp, done, theta, N);
  knn_filter<<<dim3(16, NCHUNK), 256, 0, stream>>>(train_bf, x, nt2h, theta, cnts, cand2);
  knn_vote<<<B, 256, 0, stream>>>(x, train, t2, labels, cnts, cand2, out, B, N);
}

// Round 18
// 95.320 us; speedup vs baseline: 1.9130x; 1.9130x over previous
//
#include <hip/hip_runtime.h>
#include <math.h>

// KNN (weights='distance'): B=1024 queries, N=100000 train, D=64, K=16, 10 classes.
// s-domain: s = dot - t2/2 entirely in MFMA (C-init = -t2/2); bigger = closer.
// prep (cvt | sample role-split) -> theta -> filter (64 q/block, balanced
// 1024-block grid, glds 3-slot ring depth-2, counted vmcnt, XCD-swizzle) -> vote.

constexpr int D        = 64;
constexpr int K        = 16;
constexpr int NCLS     = 10;
constexpr int CHUNKLEN = 1664;   // points per filter chunk; wave owns 416 (26 sgs of 16)
constexpr int NCHUNK   = 64;     // 64*1664 = 106496 >= 100000; %8==0; grid 16x64 = 1024 = 4/CU
constexpr int NPAD     = NCHUNK * CHUNKLEN + 64;  // 106560 (staging overrun room)
constexpr int NSUB     = 64;     // sample subchunks
constexpr int SUBLEN   = 128;    // sample points per subchunk (8192 total)
constexpr int SLOT     = 23;     // pair slots per (query, chunk); lambda ~3.25
constexpr int MSEL     = 48;     // approx candidates kept for exact rescore
constexpr int SGPTS    = 16;     // points per stage-group
constexpr int SGBYTES  = SGPTS * 128;             // 2048
constexpr int SLOTB    = SGBYTES + 256;           // ring slot: A-tile + nh = 2304
constexpr int NSG      = CHUNKLEN / 4 / SGPTS;    // 26 stage-groups per wave
constexpr int NCVT     = (NPAD * 4) / 256;        // 1665 cvt blocks (exact)

typedef __attribute__((ext_vector_type(8))) short bf16x8_t;
typedef __attribute__((ext_vector_type(4))) float f32x4_t;
typedef unsigned short ushort_t;

__device__ __forceinline__ ushort_t f32_to_bf16_rne(float f) {
  unsigned int u = __float_as_uint(f);
  unsigned int r = u + 0x7FFFu + ((u >> 16) & 1u);
  return (ushort_t)(r >> 16);
}

__device__ __forceinline__ bf16x8_t pack_bf16x8(float4 a, float4 b) {
  union { ushort_t u[8]; bf16x8_t v; } r;
  r.u[0] = f32_to_bf16_rne(a.x); r.u[1] = f32_to_bf16_rne(a.y);
  r.u[2] = f32_to_bf16_rne(a.z); r.u[3] = f32_to_bf16_rne(a.w);
  r.u[4] = f32_to_bf16_rne(b.x); r.u[5] = f32_to_bf16_rne(b.y);
  r.u[6] = f32_to_bf16_rne(b.z); r.u[7] = f32_to_bf16_rne(b.w);
  return r.v;
}

__device__ __forceinline__ void glds16(const void* g, void* l) {
  __builtin_amdgcn_global_load_lds(
      (const __attribute__((address_space(1))) void*)g,
      (__attribute__((address_space(3))) void*)l, 16, 0, 0);
}
__device__ __forceinline__ void glds4(const void* g, void* l) {
  __builtin_amdgcn_global_load_lds(
      (const __attribute__((address_space(1))) void*)g,
      (__attribute__((address_space(3))) void*)l, 4, 0, 0);
}

// ---- prep: role-split. Blocks [0,NCVT): train fp32->bf16 + t2 + nt2h
//      (pad rows: tb=0, t2=INF, nt2h=-INF). Blocks [NCVT,+1024): sample. ----
__global__ __launch_bounds__(256) void knn_prep(
    const float* __restrict__ train, const float* __restrict__ x,
    ushort_t* __restrict__ tb, float* __restrict__ t2,
    float* __restrict__ nt2h, float* __restrict__ samp, int N)
{
  __shared__ float nh_l[4][16];
  const int tid = threadIdx.x;

  if ((int)blockIdx.x < NCVT) {          // ---- cvt role ----
    int gid = blockIdx.x * 256 + tid;
    int row = gid >> 2, qt = gid & 3;
    ushort_t* dst = tb + (size_t)row * D + qt * 16;
    if (row >= N) {
      uint2 z = make_uint2(0u, 0u);
      #pragma unroll
      for (int i = 0; i < 4; ++i) *reinterpret_cast<uint2*>(dst + i * 4) = z;
      if (qt == 0) { t2[row] = INFINITY; nt2h[row] = -INFINITY; }
      return;
    }
    const float* src = train + (size_t)row * D + qt * 16;
    float nrm = 0.f;
    #pragma unroll
    for (int i = 0; i < 4; ++i) {
      float4 v = *reinterpret_cast<const float4*>(src + i * 4);
      nrm = fmaf(v.x, v.x, nrm); nrm = fmaf(v.y, v.y, nrm);
      nrm = fmaf(v.z, v.z, nrm); nrm = fmaf(v.w, v.w, nrm);
      uint2 hh = make_uint2(
        (unsigned)f32_to_bf16_rne(v.x) | ((unsigned)f32_to_bf16_rne(v.y) << 16),
        (unsigned)f32_to_bf16_rne(v.z) | ((unsigned)f32_to_bf16_rne(v.w) << 16));
      *reinterpret_cast<uint2*>(dst + i * 4) = hh;
    }
    nrm += __shfl_xor(nrm, 1);
    nrm += __shfl_xor(nrm, 2);
    if (qt == 0) { t2[row] = nrm; nt2h[row] = -0.5f * nrm; }
    return;
  }

  // ---- sample role (reads fp32 train directly; independent of cvt) ----
  const int bid2 = blockIdx.x - NCVT;
  const int w = tid >> 6, lane = tid & 63;
  const int lh = lane & 15, lg = lane >> 4;
  const int qb = bid2 & 15, sub = bid2 >> 4;
  const int q = qb * 64 + w * 16 + lh;

  const float* xrp = x + (size_t)q * D + lg * 8;
  bf16x8_t B0 = pack_bf16x8(*reinterpret_cast<const float4*>(xrp),
                            *reinterpret_cast<const float4*>(xrp + 4));
  bf16x8_t B1 = pack_bf16x8(*reinterpret_cast<const float4*>(xrp + 32),
                            *reinterpret_cast<const float4*>(xrp + 36));

  float Ld[4] = {-INFINITY, -INFINITY, -INFINITY, -INFINITY};  // descending
  const int pstart = sub * SUBLEN;

  for (int j = 0; j < SUBLEN / 16; ++j) {          // 8 groups of 16 points
    const float* tr = train + (size_t)(pstart + j * 16 + lh) * D;
    float4 f0 = *reinterpret_cast<const float4*>(tr + lg * 8);
    float4 f1 = *reinterpret_cast<const float4*>(tr + lg * 8 + 4);
    float4 f2 = *reinterpret_cast<const float4*>(tr + 32 + lg * 8);
    float4 f3 = *reinterpret_cast<const float4*>(tr + 32 + lg * 8 + 4);
    bf16x8_t A0 = pack_bf16x8(f0, f1);
    bf16x8_t A1 = pack_bf16x8(f2, f3);
    float pn = 0.f;
    pn = fmaf(f0.x, f0.x, pn); pn = fmaf(f0.y, f0.y, pn);
    pn = fmaf(f0.z, f0.z, pn); pn = fmaf(f0.w, f0.w, pn);
    pn = fmaf(f1.x, f1.x, pn); pn = fmaf(f1.y, f1.y, pn);
    pn = fmaf(f1.z, f1.z, pn); pn = fmaf(f1.w, f1.w, pn);
    pn = fmaf(f2.x, f2.x, pn); pn = fmaf(f2.y, f2.y, pn);
    pn = fmaf(f2.z, f2.z, pn); pn = fmaf(f2.w, f2.w, pn);
    pn = fmaf(f3.x, f3.x, pn); pn = fmaf(f3.y, f3.y, pn);
    pn = fmaf(f3.z, f3.z, pn); pn = fmaf(f3.w, f3.w, pn);
    pn += __shfl_xor(pn, 16);
    pn += __shfl_xor(pn, 32);      // full row norm at every lg lane
    if (lg == 0) nh_l[w][lh] = -0.5f * pn;   // within-wave LDS bounce
    float4 nh = *reinterpret_cast<const float4*>(&nh_l[w][lg * 4]);
    f32x4_t c = {nh.x, nh.y, nh.z, nh.w};
    c = __builtin_amdgcn_mfma_f32_16x16x32_bf16(A0, B0, c, 0, 0, 0);
    c = __builtin_amdgcn_mfma_f32_16x16x32_bf16(A1, B1, c, 0, 0, 0);
    #pragma unroll
    for (int r = 0; r < 4; ++r) {
      float sv = c[r];
      if (sv > Ld[3]) {
        Ld[3] = sv;
        if (Ld[3] > Ld[2]) { float s_ = Ld[3]; Ld[3] = Ld[2]; Ld[2] = s_; }
        if (Ld[2] > Ld[1]) { float s_ = Ld[2]; Ld[2] = Ld[1]; Ld[1] = s_; }
        if (Ld[1] > Ld[0]) { float s_ = Ld[1]; Ld[1] = Ld[0]; Ld[0] = s_; }
      }
    }
  }

  float* outp = samp + (size_t)q * (NSUB * 16) + sub * 16 + lg * 4;
  *reinterpret_cast<float4*>(outp) = make_float4(Ld[0], Ld[1], Ld[2], Ld[3]);
}

// ---- theta: one wave/query, 64 lanes x 4 descending-4 runs; 16 rounds of
//      wave-max pop; theta = 16th popped (tie multi-pop only loosens). ----
__global__ __launch_bounds__(256) void knn_theta(
    const float* __restrict__ samp, float* __restrict__ theta, int B)
{
  const int w = threadIdx.x >> 6, lane = threadIdx.x & 63;
  const int q = blockIdx.x * 4 + w;
  if (q >= B) return;

  const float* s = samp + (size_t)q * (NSUB * 16) + lane * 16;
  float4 p0 = *reinterpret_cast<const float4*>(s);
  float4 p1 = *reinterpret_cast<const float4*>(s + 4);
  float4 p2 = *reinterpret_cast<const float4*>(s + 8);
  float4 p3 = *reinterpret_cast<const float4*>(s + 12);
  float L0[4] = {p0.x, p0.y, p0.z, p0.w};
  float L1[4] = {p1.x, p1.y, p1.z, p1.w};
  float L2[4] = {p2.x, p2.y, p2.z, p2.w};
  float L3[4] = {p3.x, p3.y, p3.z, p3.w};

  float th = -INFINITY;
  for (int r = 0; r < K; ++r) {
    float bd = fmaxf(fmaxf(L0[0], L1[0]), fmaxf(L2[0], L3[0]));
    #pragma unroll
    for (int sdx = 0; sdx < 6; ++sdx) bd = fmaxf(bd, __shfl_xor(bd, 32 >> sdx));
    if (L0[0] == bd) { L0[0] = L0[1]; L0[1] = L0[2]; L0[2] = L0[3]; L0[3] = -INFINITY; }
    if (L1[0] == bd) { L1[0] = L1[1]; L1[1] = L1[2]; L1[2] = L1[3]; L1[3] = -INFINITY; }
    if (L2[0] == bd) { L2[0] = L2[1]; L2[1] = L2[2]; L2[2] = L2[3]; L2[3] = -INFINITY; }
    if (L3[0] == bd) { L3[0] = L3[1]; L3[1] = L3[2]; L3[2] = L3[3]; L3[3] = -INFINITY; }
    th = bd;
  }
  if (lane == 0) theta[q] = th;
}

// ---- filter: grid (16,NCHUNK)=1024 blocks (exactly 4/CU, balanced),
//      XCD-swizzled (all 16 blocks of a chunk on one XCD). Block owns 64
//      queries; wave owns 416 pts = 26 sgs of 16, staged via glds 3-slot
//      ring, depth-2 prefetch, counted vmcnt(6). Accept s >= theta. ----
__global__ __launch_bounds__(256) void knn_filter(
    const ushort_t* __restrict__ tb, const float* __restrict__ x,
    const float* __restrict__ nt2h, const float* __restrict__ theta,
    int* __restrict__ cnts, int2* __restrict__ cand2)
{
  __shared__ char ring[4][3][SLOTB];     // 27648 B
  __shared__ int  cnt_l[64];
  __shared__ int2 list_p[64][SLOT];      // 11776 B -> total ~39.7 KB, 4 blk/CU

  const int tid = threadIdx.x;
  const int w = tid >> 6, lane = tid & 63;
  const int lh = lane & 15, lg = lane >> 4;

  // XCD-aware bijective remap (NCHUNK % 8 == 0)
  const int d   = blockIdx.x + 16 * blockIdx.y;    // 0..1023
  const int xcd = d & 7;
  const int t_  = d >> 3;                          // 0..127
  const int qb  = t_ & 15;
  const int ch  = ((t_ >> 4) << 3) | xcd;          // 0..63

  const int q0  = qb * 64;
  const int wp0 = ch * CHUNKLEN + w * (CHUNKLEN / 4);   // wave's 416-pt base

  if (tid < 64) cnt_l[tid] = 0;
  __syncthreads();

  bf16x8_t Bq0[4], Bq1[4];
  float th[4];
  #pragma unroll
  for (int ct = 0; ct < 4; ++ct) {
    const float* xrp = x + (size_t)(q0 + ct * 16 + lh) * D + lg * 8;
    Bq0[ct] = pack_bf16x8(*reinterpret_cast<const float4*>(xrp),
                          *reinterpret_cast<const float4*>(xrp + 4));
    Bq1[ct] = pack_bf16x8(*reinterpret_cast<const float4*>(xrp + 32),
                          *reinterpret_cast<const float4*>(xrp + 36));
    th[ct] = theta[q0 + ct * 16 + lh];
  }

  char* myring = &ring[w][0][0];
  const char*  gA = (const char*)(tb + (size_t)wp0 * D);
  const float* gN = nt2h + wp0;
  // staging: inst k covers lds [k*1024,+1024) = 8 rows; lane l holds
  // row k*8 + l/8, swizzled 16B-slot (l&7)^(l>>3). Pre-swizzled global src.
  // => LDS[row][j] = global[row][j ^ (row&7)]; read applies the same XOR.
  const int rowoff = (lane >> 3) * 128;
  const int swz    = (((lane & 7) ^ (lane >> 3)) << 4);
  const int lhx    = lh & 7;

  #define ISSUE(SG)                                                              \
    {                                                                            \
      char* sb = myring + ((SG) % 3) * SLOTB;                                    \
      const char* ga = gA + (size_t)(SG) * SGBYTES;                              \
      glds16(ga + rowoff + swz,        sb);                                      \
      glds16(ga + 1024 + rowoff + swz, sb + 1024);                               \
      glds4 (gN + (SG) * SGPTS + lane, sb + 2048);                               \
    }

  #define COMPUTE(SG)                                                            \
    {                                                                            \
      const char* sb = myring + ((SG) % 3) * SLOTB;                              \
      bf16x8_t A0 = *reinterpret_cast<const bf16x8_t*>(                          \
          sb + lh * 128 + ((lg ^ lhx) << 4));                                    \
      bf16x8_t A1 = *reinterpret_cast<const bf16x8_t*>(                          \
          sb + lh * 128 + (((lg + 4) ^ lhx) << 4));                              \
      float4 nh = *reinterpret_cast<const float4*>(sb + 2048 + lg * 16);         \
      const int pg = wp0 + (SG) * SGPTS + lg * 4;                                \
      _Pragma("unroll")                                                          \
      for (int ct = 0; ct < 4; ++ct) {                                           \
        f32x4_t c = {nh.x, nh.y, nh.z, nh.w};                                    \
        c = __builtin_amdgcn_mfma_f32_16x16x32_bf16(A0, Bq0[ct], c, 0, 0, 0);    \
        c = __builtin_amdgcn_mfma_f32_16x16x32_bf16(A1, Bq1[ct], c, 0, 0, 0);    \
        float mx = fmaxf(fmaxf(c[0], c[1]), fmaxf(c[2], c[3]));                  \
        if (mx >= th[ct]) {                                                      \
          const int qloc = ct * 16 + lh;                                         \
          _Pragma("unroll")                                                      \
          for (int r = 0; r < 4; ++r) {                                          \
            if (c[r] >= th[ct]) {                                                \
              int pos = atomicAdd(&cnt_l[qloc], 1);                              \
              if (pos < SLOT)                                                    \
                list_p[qloc][pos] = make_int2(pg + r, __float_as_int(c[r]));     \
            }                                                                    \
          }                                                                      \
        }                                                                        \
      }                                                                          \
    }

  asm volatile("s_waitcnt vmcnt(0)" ::: "memory");   // drain prologue loads
  ISSUE(0);
  ISSUE(1);
  #pragma unroll
  for (int it = 0; it < NSG; ++it) {
    if (it < NSG - 2) {
      ISSUE(it + 2);
      asm volatile("s_waitcnt vmcnt(6)" ::: "memory");  // sg 'it' landed; 2 ahead in flight
    } else if (it == NSG - 2) {
      asm volatile("s_waitcnt vmcnt(3)" ::: "memory");
    } else {
      asm volatile("s_waitcnt vmcnt(0)" ::: "memory");
    }
    COMPUTE(it);
  }
  #undef ISSUE
  #undef COMPUTE

  __syncthreads();
  if (tid < 64) {
    int n = cnt_l[tid]; if (n > SLOT) n = SLOT;
    size_t o = (size_t)(q0 + tid) * NCHUNK + ch;
    cnts[o] = n;
    for (int j = 0; j < n; ++j) cand2[o * SLOT + j] = list_p[tid][j];
  }
}

// ---- vote: one block per query. Compact (idx,s) pairs, rank-by-count
//      (unroll-4, sentinel pad) -> top-MSEL, exact rescore (4 thr/cand),
//      exact (d2,idx)-lex top-16, weighted vote. ----
__global__ __launch_bounds__(256) void knn_vote(
    const float* __restrict__ x, const float* __restrict__ train,
    const float* __restrict__ t2, const int* __restrict__ labels,
    const int* __restrict__ cnts, const int2* __restrict__ cand2,
    float* __restrict__ out, int B, int N)
{
  __shared__ int2  cpair[NCHUNK * SLOT + 4];   // 1476 pairs
  __shared__ float sortd[MSEL];
  __shared__ int   sorti[MSEL];
  __shared__ float xs[D];
  __shared__ int   total_s;
  __shared__ float x2_s;

  const int tid = threadIdx.x;
  const int w = tid >> 6, lane = tid & 63;
  const int q = blockIdx.x;

  if (tid == 0) total_s = 0;
  if (tid < D) xs[tid] = x[(size_t)q * D + tid];
  if (tid < MSEL) { sortd[tid] = INFINITY; sorti[tid] = 0x7fffffff; }
  __syncthreads();

  if (w == 0) {
    float v = xs[lane];
    float s = v * v;
    #pragma unroll
    for (int o = 32; o > 0; o >>= 1) s += __shfl_xor(s, o);
    if (lane == 0) x2_s = s;
  }
  if (tid < NCHUNK) {
    int n = cnts[(size_t)q * NCHUNK + tid];
    int base = atomicAdd(&total_s, n);
    const int2* src = cand2 + ((size_t)q * NCHUNK + tid) * SLOT;
    for (int j = 0; j < n; ++j) cpair[base + j] = src[j];
  }
  __syncthreads();

  const int total = total_s;
  const int totalPad = (total + 3) & ~3;
  const float x2 = x2_s;
  if (tid < totalPad - total)
    cpair[total + tid] = make_int2(0x7fffffff, __float_as_int(-INFINITY));
  __syncthreads();

  for (int j = tid; j < total; j += 256) {
    int2 mine = cpair[j];
    float ms = __int_as_float(mine.y);
    int   mi = mine.x;
    int rank = 0;
    for (int k = 0; k < totalPad; k += 4) {
      int2 o0 = cpair[k];     int2 o1 = cpair[k + 1];
      int2 o2 = cpair[k + 2]; int2 o3 = cpair[k + 3];
      float s0 = __int_as_float(o0.y), s1 = __int_as_float(o1.y);
      float s2 = __int_as_float(o2.y), s3 = __int_as_float(o3.y);
      rank += ((s0 > ms || (s0 == ms && o0.x < mi)) ? 1 : 0)
            + ((s1 > ms || (s1 == ms && o1.x < mi)) ? 1 : 0)
            + ((s2 > ms || (s2 == ms && o2.x < mi)) ? 1 : 0)
            + ((s3 > ms || (s3 == ms && o3.x < mi)) ? 1 : 0);
    }
    if (rank < MSEL) { sortd[rank] = ms; sorti[rank] = mi; }
  }
  __syncthreads();

  if (tid < MSEL * 4) {
    const int ci = tid >> 2, qt = tid & 3;
    const int idx = sorti[ci];
    float dot = 0.f;
    if (idx != 0x7fffffff) {
      const float* tr = train + (size_t)idx * D + qt * 16;
      #pragma unroll
      for (int i = 0; i < 4; ++i) {
        float4 tv = *reinterpret_cast<const float4*>(tr + i * 4);
        dot = fmaf(xs[qt * 16 + i * 4 + 0], tv.x, dot);
        dot = fmaf(xs[qt * 16 + i * 4 + 1], tv.y, dot);
        dot = fmaf(xs[qt * 16 + i * 4 + 2], tv.z, dot);
        dot = fmaf(xs[qt * 16 + i * 4 + 3], tv.w, dot);
      }
    }
    dot += __shfl_xor(dot, 1);
    dot += __shfl_xor(dot, 2);
    if (qt == 0)
      sortd[ci] = (idx != 0x7fffffff)
                ? fmaxf(x2 - 2.f * dot + t2[idx], 0.f) : INFINITY;
  }
  __syncthreads();

  if (w == 0) {
    float vd = (lane < MSEL) ? sortd[lane] : INFINITY;
    int   vi = (lane < MSEL) ? sorti[lane] : 0x7fffffff;
    float myD = INFINITY; int myI = 0;
    for (int r = 0; r < K; ++r) {
      float bd = vd; int bi = vi;
      #pragma unroll
      for (int s = 0; s < 6; ++s) {
        int off = 32 >> s;
        float od = __shfl_xor(bd, off);
        int   oi = __shfl_xor(bi, off);
        if (od < bd || (od == bd && oi < bi)) { bd = od; bi = oi; }
      }
      if (vd == bd && vi == bi) { vd = INFINITY; vi = 0x7fffffff; }
      if (lane == r) { myD = bd; myI = bi; }
    }

    int valid = (lane < K) && (myD < INFINITY) && (myI < N);
    float dist = sqrtf(fmaxf(myD, 0.f));
    int lab = labels[(valid && myI < N) ? myI : 0];
    int isz = (valid && dist == 0.f) ? 1 : 0;
    float wgt = 1.f / dist;

    float accw[NCLS]; float acci[NCLS]; int anyInf = 0;
    #pragma unroll
    for (int c = 0; c < NCLS; ++c) { accw[c] = 0.f; acci[c] = 0.f; }
    for (int r = 0; r < K; ++r) {
      int   vr   = __shfl(valid, r);
      int   labr = __shfl(lab, r);
      float wgtr = __shfl(wgt, r);
      int   iszr = __shfl(isz, r);
      if (vr) {
        anyInf |= iszr;
        #pragma unroll
        for (int c = 0; c < NCLS; ++c) {
          accw[c] += (labr == c) ? wgtr : 0.f;
          acci[c] += (labr == c && iszr) ? 1.f : 0.f;
        }
      }
    }

    if (lane == 0) {
      float proba[NCLS]; float s = 0.f;
      #pragma unroll
      for (int c = 0; c < NCLS; ++c) { proba[c] = anyInf ? acci[c] : accw[c]; s += proba[c]; }
      if (s == 0.f) s = 1.f;
      #pragma unroll
      for (int c = 0; c < NCLS; ++c) proba[c] = proba[c] / s;
      int best = 0; float bv = proba[0];
      #pragma unroll
      for (int c = 1; c < NCLS; ++c) if (proba[c] > bv) { bv = proba[c]; best = c; }
      out[q] = (float)best;
      #pragma unroll
      for (int c = 0; c < NCLS; ++c) out[B + q * NCLS + c] = proba[c];
    }
  }
}

extern "C" void kernel_launch(void* const* d_in, const int* in_sizes, int n_in,
                              void* d_out, int out_size, void* d_ws, size_t ws_size,
                              hipStream_t stream)
{
  const float* x      = (const float*)d_in[0];
  const float* train  = (const float*)d_in[1];
  const int*   labels = (const int*)d_in[2];
  float* out = (float*)d_out;

  const int B = in_sizes[0] / D;   // 1024
  const int N = in_sizes[2];       // 100000

  // workspace carve (16B-aligned), ~27 MB; samp ALIASES cand2 (theta
  // consumes samp before filter writes cand2 -- stream-ordered).
  char* ws = (char*)d_ws;
  size_t off = 0;
  ushort_t* train_bf = (ushort_t*)(ws + off); off += (size_t)NPAD * D * 2;           // 13.6 MB
  float*    t2       = (float*)(ws + off);    off += (size_t)NPAD * 4;               // 426 KB
  float*    nt2h     = (float*)(ws + off);    off += (size_t)NPAD * 4;               // 426 KB
  float*    theta    = (float*)(ws + off);    off += (size_t)B * 4;
  int*      cnts     = (int*)(ws + off);      off += (size_t)B * NCHUNK * 4;         // 256 KB
  int2*     cand2    = (int2*)(ws + off);     off += (size_t)B * NCHUNK * SLOT * 8;  // 12.1 MB
  float*    samp     = (float*)cand2;         // B*NSUB*16*4 = 4 MB <= cand2 region

  knn_prep<<<NCVT + (B / 64) * NSUB, 256, 0, stream>>>(train, x, train_bf, t2, nt2h, samp, N);
  knn_theta<<<(B + 3) / 4, 256, 0, stream>>>(samp, theta, B);
  knn_filter<<<dim3(16, NCHUNK), 256, 0, stream>>>(train_bf, x, nt2h, theta, cnts, cand2);
  knn_vote<<<B, 256, 0, stream>>>(x, train, t2, labels, cnts, cand2, out, B, N);
}